// Round 3
// baseline (331.603 us; speedup 1.0000x reference)
//
#include <hip/hip_runtime.h>
#include <hip/hip_bf16.h>
#include <stdint.h>

// SingleHeadAttention: B=8 T=2048 E=1024 A=1024, fp32 in/out, bf16 MFMA inside.
// Round 3: all three GEMMs on a faithful m201 256x256 core:
//   - phases = Gray (m-half, k-sub): reads 8/4/8/4 per phase, 16 MFMA/phase
//   - lagged staging stream 2/2/2/2: A-kk1(t+1)@ph0, B-kk0(t+2)@ph1,
//     A-kk0(t+2)@ph2, B-kk1(t+2)@ph3 ; boundary s_waitcnt vmcnt(6)
//   - st_16x32 LDS swizzle (linear gload_lds dest, inverse-swizzled source)
//   - one-round grids: qkv 256 blocks (z-loop inside), pv 256 blocks
//   - 2-D XCD rectangles for qkv L2 locality

#define BB 8
#define TT 2048
#define EE 1024
#define AA 1024
#define MM (BB * TT)  // 16384

typedef short bf16x8 __attribute__((ext_vector_type(8)));
typedef float f32x4 __attribute__((ext_vector_type(4)));

#define GLOAD_LDS16(g, l)                                                      \
  __builtin_amdgcn_global_load_lds(                                            \
      (const __attribute__((address_space(1))) void*)(g),                      \
      (__attribute__((address_space(3))) void*)(l), 16, 0, 0)

#define LGKM0()                                                                \
  do {                                                                         \
    asm volatile("s_waitcnt lgkmcnt(0)" ::: "memory");                         \
    __builtin_amdgcn_sched_barrier(0);                                         \
  } while (0)

#define VMCNT(n)                                                               \
  do {                                                                         \
    asm volatile("s_waitcnt vmcnt(" #n ")" ::: "memory");                      \
    __builtin_amdgcn_sched_barrier(0);                                         \
  } while (0)

#define MFMA16(a, b, c) __builtin_amdgcn_mfma_f32_16x16x32_bf16((a), (b), (c), 0, 0, 0)

// ---------------------------------------------------------------------------
// 256x256 bt-GEMM core, BK=64, 8 waves (2m x 4n), per-wave 128x64.
// LDS per operand: [2 buf][2 ksub][256 row][32 kc] shorts, st_16x32 swizzle.
// ---------------------------------------------------------------------------
__device__ __forceinline__ void gemm_core(
    const short* __restrict__ gA, int lda, int a0row,
    const short* __restrict__ gB, int ldb, int b0row, int NT, short* As,
    short* Bs, f32x4 acc[8][4]) {
  const int tid = threadIdx.x;
  const int lane = tid & 63;
  const int w = tid >> 6;
  const int wr = w >> 2, wc = w & 3;
  const int lrow = lane & 15;
  const int lk8 = (lane >> 4) * 8;
  const int swz = ((lrow >> 3) & 1) << 4;
  const int baseA = ((wr * 128 + lrow) * 32 + lk8) ^ swz;
  const int baseB = ((wc * 64 + lrow) * 32 + lk8) ^ swz;

  // Staging: thread covers chunks 2w, 2w+1 of each 16KB region (1KB each).
  // LDS dest linear; global source pre-swizzled (involution, bit9->bit5).
  const short* pA[2];
  const short* pB[2];
  int dL[2];
#pragma unroll
  for (int i = 0; i < 2; ++i) {
    int chunk = 2 * w + i;
    int P = chunk * 1024 + lane * 16;
    int L = P ^ (((P >> 9) & 1) << 5);
    int row = L >> 6;
    int kb2 = (L & 63) >> 1;
    pA[i] = gA + (size_t)(a0row + row) * lda + kb2;
    pB[i] = gB + (size_t)(b0row + row) * ldb + kb2;
    dL[i] = chunk * 512 + lane * 8;
  }

#define STG_A(tl, s)                                                           \
  do {                                                                         \
    int _o = (tl) * 64 + (s) * 32;                                             \
    short* _d = As + (((tl) & 1) << 14) + ((s) << 13);                         \
    GLOAD_LDS16(pA[0] + _o, _d + dL[0]);                                       \
    GLOAD_LDS16(pA[1] + _o, _d + dL[1]);                                       \
  } while (0)
#define STG_B(tl, s)                                                           \
  do {                                                                         \
    int _o = (tl) * 64 + (s) * 32;                                             \
    short* _d = Bs + (((tl) & 1) << 14) + ((s) << 13);                         \
    GLOAD_LDS16(pB[0] + _o, _d + dL[0]);                                       \
    GLOAD_LDS16(pB[1] + _o, _d + dL[1]);                                       \
  } while (0)

  // Prologue: tile0 fully + tile1 minus A-kk1 (which ph0 of t=0 stages).
  STG_B(0, 0); STG_A(0, 0); STG_B(0, 1); STG_A(0, 1);
  if (NT > 1) {
    STG_B(1, 0); STG_A(1, 0); STG_B(1, 1);
    VMCNT(6);  // 14 issued; tile0's 8 complete
  } else {
    VMCNT(0);
  }
  __builtin_amdgcn_s_barrier();

  for (int t = 0; t < NT; ++t) {
    const short* Ac = As + ((t & 1) << 14);
    const short* Bc = Bs + ((t & 1) << 14);
    bf16x8 a[4], b0[4], b1[4];

    // ---- ph0: read A[kk0][mh0](4) + B[kk0](4); stage A-kk1(t+1)
#pragma unroll
    for (int m = 0; m < 4; ++m) a[m] = *(const bf16x8*)&Ac[baseA + m * 512];
#pragma unroll
    for (int n = 0; n < 4; ++n) b0[n] = *(const bf16x8*)&Bc[baseB + n * 512];
    if (t < NT - 1) STG_A(t + 1, 1);
    __builtin_amdgcn_s_barrier();
    LGKM0();
    __builtin_amdgcn_s_setprio(1);
#pragma unroll
    for (int m = 0; m < 4; ++m)
#pragma unroll
      for (int n = 0; n < 4; ++n) acc[m][n] = MFMA16(a[m], b0[n], acc[m][n]);
    __builtin_amdgcn_s_setprio(0);
    __builtin_amdgcn_s_barrier();

    // ---- ph1: read A[kk0][mh1](4); stage B-kk0(t+2)
#pragma unroll
    for (int m = 0; m < 4; ++m)
      a[m] = *(const bf16x8*)&Ac[baseA + (m + 4) * 512];
    if (t < NT - 2) STG_B(t + 2, 0);
    __builtin_amdgcn_s_barrier();
    LGKM0();
    __builtin_amdgcn_s_setprio(1);
#pragma unroll
    for (int m = 0; m < 4; ++m)
#pragma unroll
      for (int n = 0; n < 4; ++n)
        acc[m + 4][n] = MFMA16(a[m], b0[n], acc[m + 4][n]);
    __builtin_amdgcn_s_setprio(0);
    __builtin_amdgcn_s_barrier();

    // ---- ph2: read A[kk1][mh1](4) + B[kk1](4); stage A-kk0(t+2)
#pragma unroll
    for (int m = 0; m < 4; ++m)
      a[m] = *(const bf16x8*)&Ac[8192 + baseA + (m + 4) * 512];
#pragma unroll
    for (int n = 0; n < 4; ++n)
      b1[n] = *(const bf16x8*)&Bc[8192 + baseB + n * 512];
    if (t < NT - 2) STG_A(t + 2, 0);
    __builtin_amdgcn_s_barrier();
    LGKM0();
    __builtin_amdgcn_s_setprio(1);
#pragma unroll
    for (int m = 0; m < 4; ++m)
#pragma unroll
      for (int n = 0; n < 4; ++n)
        acc[m + 4][n] = MFMA16(a[m], b1[n], acc[m + 4][n]);
    __builtin_amdgcn_s_setprio(0);
    __builtin_amdgcn_s_barrier();

    // ---- ph3: read A[kk1][mh0](4); stage B-kk1(t+2); boundary vmcnt
#pragma unroll
    for (int m = 0; m < 4; ++m)
      a[m] = *(const bf16x8*)&Ac[8192 + baseA + m * 512];
    if (t < NT - 2) {
      STG_B(t + 2, 1);
      VMCNT(6);  // newest-6 = tile t+2's 3 regions; tile t+1 complete
    } else if (t == NT - 2) {
      VMCNT(0);  // tail drain (2 stale loads)
    }
    __builtin_amdgcn_s_barrier();
    LGKM0();
    __builtin_amdgcn_s_setprio(1);
#pragma unroll
    for (int m = 0; m < 4; ++m)
#pragma unroll
      for (int n = 0; n < 4; ++n) acc[m][n] = MFMA16(a[m], b1[n], acc[m][n]);
    __builtin_amdgcn_s_setprio(0);
    __builtin_amdgcn_s_barrier();
  }
#undef STG_A
#undef STG_B
}

// ---------------------------------------------------------------------------
// Fused QKV: 256 blocks (64 mt x 4 ntl), z-loop inside. XCD 2-D rectangles:
// XCD x gets 16 mt x 2 ntl (hot K-slice ~1.3 MB, L2-resident).
// ---------------------------------------------------------------------------
__global__ __launch_bounds__(512, 2) void qkv_gemm8(
    const short* __restrict__ xb, const short* __restrict__ Wb,
    short* __restrict__ qkv) {
  __shared__ __align__(16) short As[32768];
  __shared__ __align__(16) short Bs[32768];
  int f = blockIdx.x;
  int x = f & 7, j = f >> 3;
  int mt = (x >> 1) * 16 + (j >> 1);   // [0,64)
  int ntl = (x & 1) * 2 + (j & 1);     // [0,4)
  int lane = threadIdx.x & 63, w = threadIdx.x >> 6, wr = w >> 2, wc = w & 3;
  int lrow = lane & 15, lk4 = (lane >> 4) * 4;
  f32x4 acc[8][4];

  for (int z = 0; z < 3; ++z) {
#pragma unroll
    for (int m = 0; m < 8; ++m)
#pragma unroll
      for (int n = 0; n < 4; ++n) acc[m][n] = (f32x4){0.f, 0.f, 0.f, 0.f};
    gemm_core(xb, EE, mt * 256,
              Wb + (size_t)z * AA * EE + (size_t)(ntl * 256) * EE, EE, 0,
              EE / 64, As, Bs, acc);
    short* o = qkv + (size_t)z * MM * AA;
    int row0 = mt * 256 + wr * 128;
    int col0 = ntl * 256 + wc * 64;
#pragma unroll
    for (int m = 0; m < 8; ++m)
#pragma unroll
      for (int n = 0; n < 4; ++n)
#pragma unroll
        for (int r = 0; r < 4; ++r) {
          int row = row0 + m * 16 + lk4 + r;
          int col = col0 + n * 16 + lrow;
          __hip_bfloat16 h = __float2bfloat16(acc[m][n][r]);
          o[(size_t)row * AA + col] = *(short*)&h;
        }
    if (z < 2) VMCNT(0);  // keep staging vmcnt arithmetic clean next z
  }
}

// ---------------------------------------------------------------------------
// Scores: Pu = exp(scale*Q.K^T) lower-triangle tiles; rowsum atomics.
// grid 288 (8 b x 36 triangle tiles), XCD = batch.
// ---------------------------------------------------------------------------
__global__ __launch_bounds__(512, 2) void score_gemm8(
    const short* __restrict__ Qb, const short* __restrict__ Kb,
    short* __restrict__ Pu, float* __restrict__ lsum) {
  __shared__ __align__(16) short As[32768];
  __shared__ __align__(16) short Bs[32768];
  int f = blockIdx.x;
  int sidx = (f & 7) * 36 + (f >> 3);
  int b = sidx / 36;
  int f2 = sidx % 36;
  int mt = 0;
  while ((mt + 1) * (mt + 2) / 2 <= f2) ++mt;
  int nt = f2 - mt * (mt + 1) / 2;
  int lane = threadIdx.x & 63, w = threadIdx.x >> 6, wr = w >> 2, wc = w & 3;
  int lrow = lane & 15, lk4 = (lane >> 4) * 4;
  f32x4 acc[8][4];
#pragma unroll
  for (int m = 0; m < 8; ++m)
#pragma unroll
    for (int n = 0; n < 4; ++n) acc[m][n] = (f32x4){0.f, 0.f, 0.f, 0.f};
  gemm_core(Qb + (size_t)b * TT * AA, AA, mt * 256,
            Kb + (size_t)b * TT * AA, AA, nt * 256, AA / 64, As, Bs, acc);

  const float scale = 0.03125f;  // 1/sqrt(1024)
  short* P = Pu + (size_t)b * TT * TT;
  int q0 = mt * 256 + wr * 128;
  int c0 = nt * 256 + wc * 64;
#pragma unroll
  for (int m = 0; m < 8; ++m) {
#pragma unroll
    for (int r = 0; r < 4; ++r) {
      int q = q0 + m * 16 + lk4 + r;
      float rs = 0.f;
#pragma unroll
      for (int n = 0; n < 4; ++n) {
        int kx = c0 + n * 16 + lrow;
        float e = (kx <= q) ? __expf(acc[m][n][r] * scale) : 0.f;
        rs += e;
        __hip_bfloat16 h = __float2bfloat16(e);
        P[(size_t)q * TT + kx] = *(short*)&h;
      }
      rs += __shfl_xor(rs, 1);
      rs += __shfl_xor(rs, 2);
      rs += __shfl_xor(rs, 4);
      rs += __shfl_xor(rs, 8);
      if (lrow == 0) atomicAdd(&lsum[b * TT + q], rs);
    }
  }
}

// ---------------------------------------------------------------------------
// PV: out = (Pu . Vt^T-style bt) / lsum. 256 blocks (8 b x 8 mt x 4 nt),
// K = (mt+1)*256; never stages past NT (poisoned upper triangle untouched).
// ---------------------------------------------------------------------------
__global__ __launch_bounds__(512, 2) void pv_gemm8(
    const short* __restrict__ Pu, const short* __restrict__ Vt,
    const float* __restrict__ lsum, float* __restrict__ out) {
  __shared__ __align__(16) short As[32768];
  __shared__ __align__(16) short Bs[32768];
  int f = blockIdx.x;
  int b = f & 7, j = f >> 3;
  int mt = j >> 2, nt = j & 3;
  int NT = (mt + 1) * 4;
  int lane = threadIdx.x & 63, w = threadIdx.x >> 6, wr = w >> 2, wc = w & 3;
  int lrow = lane & 15, lk4 = (lane >> 4) * 4;
  f32x4 acc[8][4];
#pragma unroll
  for (int m = 0; m < 8; ++m)
#pragma unroll
    for (int n = 0; n < 4; ++n) acc[m][n] = (f32x4){0.f, 0.f, 0.f, 0.f};
  gemm_core(Pu + (size_t)b * TT * TT, TT, mt * 256,
            Vt + (size_t)b * AA * TT, TT, nt * 256, NT, As, Bs, acc);

  int q0 = mt * 256 + wr * 128;
  int d0 = nt * 256 + wc * 64;
#pragma unroll
  for (int m = 0; m < 8; ++m) {
#pragma unroll
    for (int r = 0; r < 4; ++r) {
      int q = q0 + m * 16 + lk4 + r;
      float linv = 1.0f / lsum[b * TT + q];
#pragma unroll
      for (int n = 0; n < 4; ++n) {
        int d = d0 + n * 16 + lrow;
        out[((size_t)(b * TT + q)) * AA + d] = acc[m][n][r] * linv;
      }
    }
  }
}

// ---------------------------------------------------------------------------
// cvt + V transpose (unchanged from round 2)
// ---------------------------------------------------------------------------
__global__ void cvt_bf16(const float* __restrict__ src, short* __restrict__ dst,
                         int n4) {
  int stride = gridDim.x * blockDim.x;
  for (int i = blockIdx.x * blockDim.x + threadIdx.x; i < n4; i += stride) {
    float4 v = ((const float4*)src)[i];
    __hip_bfloat16 h0 = __float2bfloat16(v.x);
    __hip_bfloat16 h1 = __float2bfloat16(v.y);
    __hip_bfloat16 h2 = __float2bfloat16(v.z);
    __hip_bfloat16 h3 = __float2bfloat16(v.w);
    short4 o;
    o.x = *(short*)&h0;
    o.y = *(short*)&h1;
    o.z = *(short*)&h2;
    o.w = *(short*)&h3;
    ((short4*)dst)[i] = o;
  }
}

__global__ __launch_bounds__(256) void transpose_v(const short* __restrict__ Vb,
                                                   short* __restrict__ Vt) {
  __shared__ __align__(16) short lds[64 * 72];
  int t0 = blockIdx.x * 64;
  int d0 = blockIdx.y * 64;
  int b = blockIdx.z;
  int tid = threadIdx.x;
  const short* src = Vb + ((size_t)b * TT + t0) * AA + d0;
#pragma unroll
  for (int r = 0; r < 2; ++r) {
    int t = r * 256 + tid;
    int row = t >> 3;
    int c = (t & 7) * 8;
    *(bf16x8*)&lds[row * 72 + c] = *(const bf16x8*)&src[(size_t)row * AA + c];
  }
  __syncthreads();
  short* dst = Vt + ((size_t)b * AA + d0) * TT + t0;
#pragma unroll
  for (int r = 0; r < 2; ++r) {
    int t = r * 256 + tid;
    int d = t >> 3;
    int c = (t & 7) * 8;
    bf16x8 wv;
#pragma unroll
    for (int e = 0; e < 8; ++e) wv[e] = lds[(c + e) * 72 + d];
    *(bf16x8*)&dst[(size_t)d * TT + c] = wv;
  }
}

extern "C" void kernel_launch(void* const* d_in, const int* in_sizes, int n_in,
                              void* d_out, int out_size, void* d_ws,
                              size_t ws_size, hipStream_t stream) {
  const float* x = (const float*)d_in[0];
  const float* Wq = (const float*)d_in[1];
  const float* Wk = (const float*)d_in[2];
  const float* Wv = (const float*)d_in[3];

  char* ws = (char*)d_ws;
  size_t oWb = 0;
  size_t oQb = oWb + (size_t)3 * AA * EE * 2;
  size_t oKb = oQb + (size_t)MM * AA * 2;
  size_t oVb = oKb + (size_t)MM * AA * 2;
  size_t oVt = oVb + (size_t)MM * AA * 2;
  size_t oLs = oVt + (size_t)MM * AA * 2;
  size_t oXb = oLs + (size_t)MM * 4;
  size_t oPu = oXb;  // Pu overlaps Xb (dead after qkv)

  short* Wb = (short*)(ws + oWb);
  short* Qb = (short*)(ws + oQb);
  short* Kb = (short*)(ws + oKb);
  short* Vb = (short*)(ws + oVb);
  short* Vt = (short*)(ws + oVt);
  float* Ls = (float*)(ws + oLs);
  short* Xb = (short*)(ws + oXb);
  short* Pu = (short*)(ws + oPu);

  cvt_bf16<<<2048, 256, 0, stream>>>(x, Xb, MM * EE / 4);
  cvt_bf16<<<512, 256, 0, stream>>>(Wq, Wb, AA * EE / 4);
  cvt_bf16<<<512, 256, 0, stream>>>(Wk, Wb + (size_t)AA * EE, AA * EE / 4);
  cvt_bf16<<<512, 256, 0, stream>>>(Wv, Wb + (size_t)2 * AA * EE, AA * EE / 4);
  hipMemsetAsync(Ls, 0, (size_t)MM * 4, stream);

  qkv_gemm8<<<256, 512, 0, stream>>>(Xb, Wb, Qb);
  transpose_v<<<dim3(32, 16, 8), 256, 0, stream>>>(Vb, Vt);
  score_gemm8<<<288, 512, 0, stream>>>(Qb, Kb, Pu, Ls);
  pv_gemm8<<<256, 512, 0, stream>>>(Pu, Vt, Ls, (float*)d_out);
}